// Round 1
// baseline (804.743 us; speedup 1.0000x reference)
//
#include <hip/hip_runtime.h>
#include <cstdint>
#include <cstddef>

#define NEG_SLOPE 0.2f

// ---------- helpers ----------
__device__ __forceinline__ unsigned enc_f(float f) {
  unsigned u = __float_as_uint(f);
  return (u & 0x80000000u) ? ~u : (u | 0x80000000u);
}
__device__ __forceinline__ float dec_f(unsigned u) {
  u = (u & 0x80000000u) ? (u & 0x7FFFFFFFu) : ~u;
  return __uint_as_float(u);
}

// ---------- generic tiled fp32 GEMM: C[M][Nc] = A[M][K] @ B[K][Nc] ----------
// BM=BN=BK=64, 256 threads, 4x4 micro-tile per thread, float4 LDS reads.
__global__ __launch_bounds__(256) void gemm_tiled(
    const float* __restrict__ A, const float* __restrict__ B,
    float* __restrict__ C, int M, int K, int Nc) {
  const int BM = 64, BN = 64, BK = 64, PAD = 4;
  __shared__ float As[BK][BM + PAD];  // transposed: As[k][row]
  __shared__ float Bs[BK][BN + PAD];
  int tid = threadIdx.x;
  int tx = tid & 15, ty = tid >> 4;
  int row0 = blockIdx.x * BM;
  int col0 = blockIdx.y * BN;
  float acc[4][4] = {};
  for (int k0 = 0; k0 < K; k0 += BK) {
    #pragma unroll
    for (int l = 0; l < (BM * BK) / 256; l++) {
      int flat = tid + 256 * l;
      int r = flat >> 6, k = flat & 63;  // consecutive tid -> consecutive k
      int gr = row0 + r;
      float v = (gr < M) ? A[(size_t)gr * K + k0 + k] : 0.f;
      As[k][r] = v;
    }
    #pragma unroll
    for (int l = 0; l < (BK * BN) / 256; l++) {
      int flat = tid + 256 * l;
      int k = flat >> 6, c = flat & 63;  // consecutive tid -> consecutive c
      Bs[k][c] = B[(size_t)(k0 + k) * Nc + col0 + c];
    }
    __syncthreads();
    #pragma unroll
    for (int k = 0; k < BK; k++) {
      float4 a = *(const float4*)&As[k][ty * 4];
      float4 b = *(const float4*)&Bs[k][tx * 4];
      acc[0][0] += a.x * b.x; acc[0][1] += a.x * b.y; acc[0][2] += a.x * b.z; acc[0][3] += a.x * b.w;
      acc[1][0] += a.y * b.x; acc[1][1] += a.y * b.y; acc[1][2] += a.y * b.z; acc[1][3] += a.y * b.w;
      acc[2][0] += a.z * b.x; acc[2][1] += a.z * b.y; acc[2][2] += a.z * b.z; acc[2][3] += a.z * b.w;
      acc[3][0] += a.w * b.x; acc[3][1] += a.w * b.y; acc[3][2] += a.w * b.z; acc[3][3] += a.w * b.w;
    }
    __syncthreads();
  }
  #pragma unroll
  for (int i = 0; i < 4; i++) {
    int gr = row0 + ty * 4 + i;
    if (gr < M) {
      float4 v = make_float4(acc[i][0], acc[i][1], acc[i][2], acc[i][3]);
      *(float4*)&C[(size_t)gr * Nc + col0 + tx * 4] = v;
    }
  }
}

// ---------- per-(node,head) attention dots: wave per (n,h), 64 lanes = channels ----------
template <int H>
__global__ __launch_bounds__(256) void attn_dots(
    const float* __restrict__ h, const float* __restrict__ att_s,
    const float* __restrict__ att_d, float* __restrict__ as_out,
    float* __restrict__ ad_out, int n) {
  int wave = (int)((blockIdx.x * blockDim.x + threadIdx.x) >> 6);
  int lane = threadIdx.x & 63;
  if (wave >= n * H) return;
  int node = wave / H, hd = wave % H;
  float v = h[(size_t)node * (H * 64) + hd * 64 + lane];
  float s = v * att_s[hd * 64 + lane];
  float d = v * att_d[hd * 64 + lane];
  #pragma unroll
  for (int off = 32; off; off >>= 1) {
    s += __shfl_down(s, off, 64);
    d += __shfl_down(d, off, 64);
  }
  if (lane == 0) { as_out[wave] = s; ad_out[wave] = d; }
}

// ---------- CSR build ----------
__global__ void count_dst(const int* __restrict__ ei, int* __restrict__ counts,
                          int E, int ET) {
  int i = blockIdx.x * blockDim.x + threadIdx.x;
  if (i >= ET) return;
  int dst = (i < E) ? ei[E + i] : (i - E);
  atomicAdd(&counts[dst], 1);
}

__global__ __launch_bounds__(1024) void scan_offsets(
    const int* __restrict__ counts, int* __restrict__ offsets, int n) {
  __shared__ int sums[1024];
  int t = threadIdx.x;
  int chunk = (n + 1023) >> 10;
  int start = t * chunk;
  int end = min(start + chunk, n);
  int s = 0;
  for (int i = start; i < end; i++) s += counts[i];
  sums[t] = s;
  __syncthreads();
  for (int off = 1; off < 1024; off <<= 1) {
    int v = (t >= off) ? sums[t - off] : 0;
    __syncthreads();
    sums[t] += v;
    __syncthreads();
  }
  int run = sums[t] - s;  // exclusive prefix
  for (int i = start; i < end; i++) { offsets[i] = run; run += counts[i]; }
  if (t == 1023) offsets[n] = sums[1023];
}

__global__ void fill_elist(const int* __restrict__ ei, const int* __restrict__ offsets,
                           int* __restrict__ cursor, int* __restrict__ elist,
                           int E, int ET) {
  int i = blockIdx.x * blockDim.x + threadIdx.x;
  if (i >= ET) return;
  int dst = (i < E) ? ei[E + i] : (i - E);
  int pos = atomicAdd(&cursor[dst], 1);
  elist[offsets[dst] + pos] = i;
}

// ---------- edge softmax, pass 1: logits + segment max ----------
template <int H>
__global__ void edge_logits(const int* __restrict__ ei, const float* __restrict__ as,
                            const float* __restrict__ ad, float* __restrict__ ebuf,
                            unsigned* __restrict__ emax, int E, int ET) {
  int idx = blockIdx.x * blockDim.x + threadIdx.x;
  if (idx >= ET * H) return;
  int e = idx / H, hd = idx % H;
  int src, dst;
  if (e < E) { src = ei[e]; dst = ei[E + e]; } else { src = dst = e - E; }
  float v = as[src * H + hd] + ad[dst * H + hd];
  v = (v > 0.f) ? v : NEG_SLOPE * v;
  ebuf[idx] = v;
  atomicMax(&emax[dst * H + hd], enc_f(v));
}

// ---------- edge softmax, pass 2: exp + denom ----------
template <int H>
__global__ void edge_exp(const int* __restrict__ ei, const unsigned* __restrict__ emax,
                         float* __restrict__ ebuf, float* __restrict__ denom,
                         int E, int ET) {
  int idx = blockIdx.x * blockDim.x + threadIdx.x;
  if (idx >= ET * H) return;
  int e = idx / H, hd = idx % H;
  int dst = (e < E) ? ei[E + e] : (e - E);
  float m = dec_f(emax[dst * H + hd]);
  float v = __expf(ebuf[idx] - m);
  ebuf[idx] = v;
  atomicAdd(&denom[dst * H + hd], v);
}

// ---------- layer-1 aggregation: block per dst node; 8 heads x 64 ch ----------
__global__ __launch_bounds__(256) void aggregate1(
    const int* __restrict__ ei, const int* __restrict__ offsets,
    const int* __restrict__ elist, const float* __restrict__ ebuf,
    const float* __restrict__ denom, const float* __restrict__ hfeat,
    const float* __restrict__ b1, float* __restrict__ z, int E) {
  int node = blockIdx.x;
  int tid = threadIdx.x;
  __shared__ float red[512];
  int beg = offsets[node], end = offsets[node + 1];
  int f0 = tid, f1 = tid + 256;
  int h0 = f0 >> 6, h1 = f1 >> 6;
  float inv0 = 1.f / denom[node * 8 + h0];
  float inv1 = 1.f / denom[node * 8 + h1];
  float acc0 = 0.f, acc1 = 0.f;
  for (int j = beg; j < end; j++) {
    int eid = elist[j];
    int src = (eid < E) ? ei[eid] : (eid - E);
    float w0 = ebuf[eid * 8 + h0];
    float w1 = ebuf[eid * 8 + h1];
    const float* hp = &hfeat[(size_t)src * 512];
    acc0 += w0 * hp[f0];
    acc1 += w1 * hp[f1];
  }
  red[f0] = acc0 * inv0;
  red[f1] = acc1 * inv1;
  __syncthreads();
  if (tid < 64) {
    float s = 0.f;
    #pragma unroll
    for (int hh = 0; hh < 8; hh++) s += red[hh * 64 + tid];
    s = s * 0.125f + b1[tid];
    // ELU
    z[(size_t)node * 64 + tid] = (s > 0.f) ? s : (__expf(s) - 1.f);
  }
}

// ---------- layer-2 aggregation: wave per dst node, 1 head x 64 ch ----------
__global__ __launch_bounds__(256) void aggregate2(
    const int* __restrict__ ei, const int* __restrict__ offsets,
    const int* __restrict__ elist, const float* __restrict__ ebuf,
    const float* __restrict__ denom, const float* __restrict__ hfeat,
    const float* __restrict__ b2, float* __restrict__ out, int E, int n) {
  int wid = (int)((blockIdx.x * blockDim.x + threadIdx.x) >> 6);
  int lane = threadIdx.x & 63;
  if (wid >= n) return;
  int beg = offsets[wid], end = offsets[wid + 1];
  float inv = 1.f / denom[wid];
  float acc = 0.f;
  for (int j = beg; j < end; j++) {
    int eid = elist[j];
    int src = (eid < E) ? ei[eid] : (eid - E);
    acc += ebuf[eid] * hfeat[(size_t)src * 64 + lane];
  }
  out[(size_t)wid * 64 + lane] = acc * inv + b2[lane];
}

// ---------- host launch ----------
extern "C" void kernel_launch(void* const* d_in, const int* in_sizes, int n_in,
                              void* d_out, int out_size, void* d_ws, size_t ws_size,
                              hipStream_t stream) {
  const int IN = 128, OUT = 64, H = 8;
  const int N = in_sizes[0] / IN;      // 50000
  const int E = in_sizes[1] / 2;       // 400000
  const int ET = E + N;                // with self-loops

  const float* x        = (const float*)d_in[0];
  const int*   ei       = (const int*)d_in[1];
  const float* W1       = (const float*)d_in[2];
  const float* att_src1 = (const float*)d_in[3];
  const float* att_dst1 = (const float*)d_in[4];
  const float* b1       = (const float*)d_in[5];
  const float* W2       = (const float*)d_in[6];
  const float* att_src2 = (const float*)d_in[7];
  const float* att_dst2 = (const float*)d_in[8];
  const float* b2       = (const float*)d_in[9];
  float* out = (float*)d_out;

  // workspace layout
  char* base = (char*)d_ws;
  size_t off = 0;
  auto alloc = [&](size_t bytes) -> char* {
    char* p = base + off;
    off = (off + bytes + 255) & ~(size_t)255;
    return p;
  };
  float*    h1      = (float*)alloc((size_t)N * 512 * 4);
  float*    z       = (float*)alloc((size_t)N * 64 * 4);
  float*    h2      = (float*)alloc((size_t)N * 64 * 4);
  float*    a_s1    = (float*)alloc((size_t)N * 8 * 4);
  float*    a_d1    = (float*)alloc((size_t)N * 8 * 4);
  float*    a_s2    = (float*)alloc((size_t)N * 4);
  float*    a_d2    = (float*)alloc((size_t)N * 4);
  float*    ebuf1   = (float*)alloc((size_t)ET * 8 * 4);
  float*    ebuf2   = (float*)alloc((size_t)ET * 4);
  int*      offsets = (int*)alloc((size_t)(N + 1) * 4);
  int*      elist   = (int*)alloc((size_t)ET * 4);
  char* zero_begin = base + off;
  unsigned* emax1   = (unsigned*)alloc((size_t)N * 8 * 4);
  float*    denom1  = (float*)alloc((size_t)N * 8 * 4);
  unsigned* emax2   = (unsigned*)alloc((size_t)N * 4);
  float*    denom2  = (float*)alloc((size_t)N * 4);
  int*      counts  = (int*)alloc((size_t)N * 4);
  int*      cursor  = (int*)alloc((size_t)N * 4);
  char* zero_end = base + off;

  // zero the atomics block (emax sortable-encoding: 0 < enc(any finite float))
  hipMemsetAsync(zero_begin, 0, (size_t)(zero_end - zero_begin), stream);

  const int TB = 256;
  auto cdiv = [](int a, int b) { return (a + b - 1) / b; };

  // --- layer 1 ---
  {
    dim3 g(cdiv(N, 64), 512 / 64);
    gemm_tiled<<<g, TB, 0, stream>>>(x, W1, h1, N, IN, 512);
  }
  attn_dots<8><<<cdiv(N * 8, 4), TB, 0, stream>>>(h1, att_src1, att_dst1, a_s1, a_d1, N);

  count_dst<<<cdiv(ET, TB), TB, 0, stream>>>(ei, counts, E, ET);
  scan_offsets<<<1, 1024, 0, stream>>>(counts, offsets, N);
  fill_elist<<<cdiv(ET, TB), TB, 0, stream>>>(ei, offsets, cursor, elist, E, ET);

  edge_logits<8><<<cdiv(ET * 8, TB), TB, 0, stream>>>(ei, a_s1, a_d1, ebuf1, emax1, E, ET);
  edge_exp<8><<<cdiv(ET * 8, TB), TB, 0, stream>>>(ei, emax1, ebuf1, denom1, E, ET);
  aggregate1<<<N, TB, 0, stream>>>(ei, offsets, elist, ebuf1, denom1, h1, b1, z, E);

  // --- layer 2 ---
  {
    dim3 g(cdiv(N, 64), 1);
    gemm_tiled<<<g, TB, 0, stream>>>(z, W2, h2, N, OUT, 64);
  }
  attn_dots<1><<<cdiv(N, 4), TB, 0, stream>>>(h2, att_src2, att_dst2, a_s2, a_d2, N);
  edge_logits<1><<<cdiv(ET, TB), TB, 0, stream>>>(ei, a_s2, a_d2, ebuf2, emax2, E, ET);
  edge_exp<1><<<cdiv(ET, TB), TB, 0, stream>>>(ei, emax2, ebuf2, denom2, E, ET);
  aggregate2<<<cdiv(N, 4), TB, 0, stream>>>(ei, offsets, elist, ebuf2, denom2, h2, b2, out, E, N);
}

// Round 2
// 453.586 us; speedup vs baseline: 1.7742x; 1.7742x over previous
//
#include <hip/hip_runtime.h>
#include <cstdint>
#include <cstddef>

#define NEG_SLOPE 0.2f

typedef short bf16x8 __attribute__((ext_vector_type(8)));
typedef float f32x4 __attribute__((ext_vector_type(4)));

// ---------- bf16 <-> f32 helpers (bit-level, RNE) ----------
__device__ __forceinline__ unsigned short f2bf(float f) {
  unsigned u = __float_as_uint(f);
  u = u + 0x7FFFu + ((u >> 16) & 1u);
  return (unsigned short)(u >> 16);
}
__device__ __forceinline__ float bf2f(unsigned short b) {
  return __uint_as_float((unsigned)b << 16);
}

// ---------- casts ----------
__global__ void cast4(const float* __restrict__ in, unsigned short* __restrict__ outp,
                      int n4) {
  int i = blockIdx.x * blockDim.x + threadIdx.x;
  if (i >= n4) return;
  float4 v = ((const float4*)in)[i];
  ushort4 o;
  o.x = f2bf(v.x); o.y = f2bf(v.y); o.z = f2bf(v.z); o.w = f2bf(v.w);
  ((ushort4*)outp)[i] = o;
}

// W[K][Nc] fp32 -> Wt[Nc][K] bf16
__global__ void cast_t(const float* __restrict__ W, unsigned short* __restrict__ Wt,
                       int K, int Nc) {
  int i = blockIdx.x * blockDim.x + threadIdx.x;
  if (i >= K * Nc) return;
  int k = i / Nc, nn = i % Nc;
  Wt[(size_t)nn * K + k] = f2bf(W[i]);
}

// ---------- fused GEMM + attention dots ----------
// C[M][H*64] = A[M][K] @ W (W given transposed: Wt[H*64][K]), K = KS*32.
// Block: 256 thr = 4 waves; wave w -> rows [bx*64+w*16, +16), cols = head hd's 64.
// Stores H bf16 and per-(row,head) attention dots a_s, a_d (fp32 accum).
template <int KS, int H>
__global__ __launch_bounds__(256) void gemm_attn(
    const unsigned short* __restrict__ Ab,   // [M][K] bf16
    const unsigned short* __restrict__ Wt,   // [H*64][K] bf16
    const float* __restrict__ atts,          // [H][64]
    const float* __restrict__ attd,          // [H][64]
    unsigned short* __restrict__ Hout,       // [M][H*64] bf16
    float* __restrict__ as_out,              // [M][H]
    float* __restrict__ ad_out,              // [M][H]
    int M) {
  const int K = KS * 32;
  int wave = threadIdx.x >> 6, lane = threadIdx.x & 63;
  int q = lane >> 4, t = lane & 15;
  int hd = blockIdx.y;
  int row0 = blockIdx.x * 64 + wave * 16;

  int arow = row0 + t; if (arow > M - 1) arow = M - 1;
  const bf16x8* aptr = (const bf16x8*)(Ab + (size_t)arow * K);
  bf16x8 afr[KS];
  #pragma unroll
  for (int s = 0; s < KS; s++) afr[s] = aptr[s * 4 + q];

  f32x4 acc[4];
  #pragma unroll
  for (int c = 0; c < 4; c++) acc[c] = (f32x4){0.f, 0.f, 0.f, 0.f};
  #pragma unroll
  for (int c = 0; c < 4; c++) {
    const bf16x8* bptr = (const bf16x8*)(Wt + (size_t)(hd * 64 + c * 16 + t) * K);
    #pragma unroll
    for (int s = 0; s < KS; s++) {
      acc[c] = __builtin_amdgcn_mfma_f32_16x16x32_bf16(afr[s], bptr[s * 4 + q],
                                                       acc[c], 0, 0, 0);
    }
  }

  // epilogue: store bf16 + attention partial dots
  float ps[4] = {0, 0, 0, 0}, pd[4] = {0, 0, 0, 0};
  #pragma unroll
  for (int c = 0; c < 4; c++) {
    int col = c * 16 + t;
    float ws = atts[hd * 64 + col], wd = attd[hd * 64 + col];
    #pragma unroll
    for (int r = 0; r < 4; r++) {
      float v = acc[c][r];
      int row = row0 + q * 4 + r;
      if (row < M) Hout[(size_t)row * (H * 64) + hd * 64 + col] = f2bf(v);
      ps[r] += v * ws;
      pd[r] += v * wd;
    }
  }
  // reduce over the 16 lanes of this quad (cols 0..63 of the head)
  #pragma unroll
  for (int r = 0; r < 4; r++) {
    float s = ps[r], d = pd[r];
    #pragma unroll
    for (int off = 1; off < 16; off <<= 1) {
      s += __shfl_xor(s, off, 64);
      d += __shfl_xor(d, off, 64);
    }
    int row = row0 + q * 4 + r;
    if (t == 0 && row < M) {
      as_out[row * H + hd] = s;
      ad_out[row * H + hd] = d;
    }
  }
}

// ---------- CSR build ----------
__global__ void count_dst(const int* __restrict__ ei, int* __restrict__ counts,
                          int E, int ET) {
  int i = blockIdx.x * blockDim.x + threadIdx.x;
  if (i >= ET) return;
  int dst = (i < E) ? ei[E + i] : (i - E);
  atomicAdd(&counts[dst], 1);
}

__global__ __launch_bounds__(1024) void scan_offsets(
    const int* __restrict__ counts, int* __restrict__ offsets, int n) {
  __shared__ int sums[1024];
  int t = threadIdx.x;
  int chunk = (n + 1023) >> 10;
  int start = t * chunk;
  int end = min(start + chunk, n);
  int s = 0;
  for (int i = start; i < end; i++) s += counts[i];
  sums[t] = s;
  __syncthreads();
  for (int off = 1; off < 1024; off <<= 1) {
    int v = (t >= off) ? sums[t - off] : 0;
    __syncthreads();
    sums[t] += v;
    __syncthreads();
  }
  int run = sums[t] - s;  // exclusive prefix
  for (int i = start; i < end; i++) { offsets[i] = run; run += counts[i]; }
  if (t == 1023) offsets[n] = sums[1023];
}

__global__ void fill_srcs(const int* __restrict__ ei, const int* __restrict__ offsets,
                          int* __restrict__ cursor, int* __restrict__ srcs,
                          int E, int ET) {
  int i = blockIdx.x * blockDim.x + threadIdx.x;
  if (i >= ET) return;
  int src, dst;
  if (i < E) { src = ei[i]; dst = ei[E + i]; } else { src = dst = i - E; }
  int pos = atomicAdd(&cursor[dst], 1);
  srcs[offsets[dst] + pos] = src;
}

// ---------- layer-1 aggregation (fused edge softmax, no max-subtraction) ----------
// block per dst node; 256 thr, thread t -> channels 2t,2t+1 (head = 2t>>6).
__global__ __launch_bounds__(256) void aggregate1(
    const int* __restrict__ offsets, const int* __restrict__ srcs,
    const float* __restrict__ as1, const float* __restrict__ ad1,
    const unsigned short* __restrict__ h1, const float* __restrict__ b1,
    unsigned short* __restrict__ z) {
  int node = blockIdx.x;
  int tid = threadIdx.x;
  int f = tid * 2;
  int h = f >> 6;
  float adv = ad1[node * 8 + h];
  int beg = offsets[node], end = offsets[node + 1];
  float acc0 = 0.f, acc1 = 0.f, accw = 0.f;
  for (int j = beg; j < end; j++) {
    int src = srcs[j];
    float v = as1[src * 8 + h] + adv;
    v = (v > 0.f) ? v : NEG_SLOPE * v;
    float w = __expf(v);
    accw += w;
    unsigned hv = *(const unsigned*)&h1[(size_t)src * 512 + f];
    acc0 += w * bf2f((unsigned short)(hv & 0xFFFFu));
    acc1 += w * bf2f((unsigned short)(hv >> 16));
  }
  float inv = 1.0f / accw;
  __shared__ float red[512];
  red[f] = acc0 * inv;
  red[f + 1] = acc1 * inv;
  __syncthreads();
  if (tid < 32) {
    int c0 = tid * 2, c1 = c0 + 1;
    float s0 = 0.f, s1 = 0.f;
    #pragma unroll
    for (int hh = 0; hh < 8; hh++) { s0 += red[hh * 64 + c0]; s1 += red[hh * 64 + c1]; }
    s0 = 0.125f * s0 + b1[c0];
    s1 = 0.125f * s1 + b1[c1];
    s0 = (s0 > 0.f) ? s0 : (__expf(s0) - 1.f);  // ELU
    s1 = (s1 > 0.f) ? s1 : (__expf(s1) - 1.f);
    unsigned o = (unsigned)f2bf(s0) | ((unsigned)f2bf(s1) << 16);
    *(unsigned*)&z[(size_t)node * 64 + c0] = o;
  }
}

// ---------- layer-2 aggregation: wave per dst node ----------
__global__ __launch_bounds__(256) void aggregate2(
    const int* __restrict__ offsets, const int* __restrict__ srcs,
    const float* __restrict__ as2, const float* __restrict__ ad2,
    const unsigned short* __restrict__ h2, const float* __restrict__ b2,
    float* __restrict__ out, int n) {
  int wid = (int)((blockIdx.x * blockDim.x + threadIdx.x) >> 6);
  int lane = threadIdx.x & 63;
  if (wid >= n) return;
  float adv = ad2[wid];
  int beg = offsets[wid], end = offsets[wid + 1];
  float acc = 0.f, accw = 0.f;
  for (int j = beg; j < end; j++) {
    int src = srcs[j];
    float v = as2[src] + adv;
    v = (v > 0.f) ? v : NEG_SLOPE * v;
    float w = __expf(v);
    accw += w;
    acc += w * bf2f(h2[(size_t)src * 64 + lane]);
  }
  out[(size_t)wid * 64 + lane] = acc / accw + b2[lane];
}

// ---------- host launch ----------
extern "C" void kernel_launch(void* const* d_in, const int* in_sizes, int n_in,
                              void* d_out, int out_size, void* d_ws, size_t ws_size,
                              hipStream_t stream) {
  const int IN = 128, H = 8;
  const int N = in_sizes[0] / IN;      // 50000
  const int E = in_sizes[1] / 2;       // 400000
  const int ET = E + N;                // with self-loops

  const float* x        = (const float*)d_in[0];
  const int*   ei       = (const int*)d_in[1];
  const float* W1       = (const float*)d_in[2];
  const float* att_src1 = (const float*)d_in[3];
  const float* att_dst1 = (const float*)d_in[4];
  const float* b1       = (const float*)d_in[5];
  const float* W2       = (const float*)d_in[6];
  const float* att_src2 = (const float*)d_in[7];
  const float* att_dst2 = (const float*)d_in[8];
  const float* b2       = (const float*)d_in[9];
  float* out = (float*)d_out;

  // workspace layout
  char* base = (char*)d_ws;
  size_t off = 0;
  auto alloc = [&](size_t bytes) -> char* {
    char* p = base + off;
    off = (off + bytes + 255) & ~(size_t)255;
    return p;
  };
  unsigned short* xb   = (unsigned short*)alloc((size_t)N * 128 * 2);
  unsigned short* W1t  = (unsigned short*)alloc((size_t)512 * 128 * 2);
  unsigned short* W2t  = (unsigned short*)alloc((size_t)64 * 64 * 2);
  unsigned short* h1   = (unsigned short*)alloc((size_t)N * 512 * 2);
  unsigned short* z    = (unsigned short*)alloc((size_t)N * 64 * 2);
  unsigned short* h2   = (unsigned short*)alloc((size_t)N * 64 * 2);
  float* a_s1 = (float*)alloc((size_t)N * 8 * 4);
  float* a_d1 = (float*)alloc((size_t)N * 8 * 4);
  float* a_s2 = (float*)alloc((size_t)N * 4);
  float* a_d2 = (float*)alloc((size_t)N * 4);
  int* offsets = (int*)alloc((size_t)(N + 1) * 4);
  int* srcs    = (int*)alloc((size_t)ET * 4);
  char* zero_begin = base + off;
  int* counts  = (int*)alloc((size_t)N * 4);
  int* cursor  = (int*)alloc((size_t)N * 4);
  char* zero_end = base + off;

  hipMemsetAsync(zero_begin, 0, (size_t)(zero_end - zero_begin), stream);

  const int TB = 256;
  auto cdiv = [](int a, int b) { return (a + b - 1) / b; };

  // CSR build (independent of feature pipeline)
  count_dst<<<cdiv(ET, TB), TB, 0, stream>>>(ei, counts, E, ET);
  scan_offsets<<<1, 1024, 0, stream>>>(counts, offsets, N);
  fill_srcs<<<cdiv(ET, TB), TB, 0, stream>>>(ei, offsets, cursor, srcs, E, ET);

  // casts
  cast4<<<cdiv(N * 128 / 4, TB), TB, 0, stream>>>(x, xb, N * 128 / 4);
  cast_t<<<cdiv(128 * 512, TB), TB, 0, stream>>>(W1, W1t, 128, 512);
  cast_t<<<cdiv(64 * 64, TB), TB, 0, stream>>>(W2, W2t, 64, 64);

  // layer 1
  {
    dim3 g(cdiv(N, 64), H);
    gemm_attn<4, 8><<<g, TB, 0, stream>>>(xb, W1t, att_src1, att_dst1,
                                          h1, a_s1, a_d1, N);
  }
  aggregate1<<<N, TB, 0, stream>>>(offsets, srcs, a_s1, a_d1, h1, b1, z);

  // layer 2
  {
    dim3 g(cdiv(N, 64), 1);
    gemm_attn<2, 1><<<g, TB, 0, stream>>>(z, W2t, att_src2, att_dst2,
                                          h2, a_s2, a_d2, N);
  }
  aggregate2<<<cdiv(N, 4), TB, 0, stream>>>(offsets, srcs, a_s2, a_d2, h2, b2,
                                            out, N);
}